// Round 1
// baseline (156.470 us; speedup 1.0000x reference)
//
#include <hip/hip_runtime.h>
#include <stdint.h>

#define Nn 8192
#define Dd 256
#define Ss 4096
#define Cc 65

#define TI 128
#define TJ 128
#define BK 32
#define CHUNK 512
#define NCHUNK (Nn / CHUNK)   // 16
#define NJT (CHUNK / TJ)      // 4
#define KS (Dd / BK)          // 8

#define BIGF 3.0e37f

typedef float f4 __attribute__((ext_vector_type(4)));
typedef __bf16 bf8 __attribute__((ext_vector_type(8)));

__device__ __forceinline__ float wredsum(float v) {
#pragma unroll
  for (int o = 32; o; o >>= 1) v += __shfl_xor(v, o, 64);
  return v;
}
__device__ __forceinline__ float wredmax(float v) {
#pragma unroll
  for (int o = 32; o; o >>= 1) v = fmaxf(v, __shfl_xor(v, o, 64));
  return v;
}

__device__ __forceinline__ unsigned short f2bf(float f) {
  unsigned int u = __float_as_uint(f);
  u = (u + 0x7fffu + ((u >> 16) & 1u)) >> 16;
  return (unsigned short)u;
}

__device__ __forceinline__ void merge5(const float* a, const float* b, float* o) {
  o[0] = fminf(a[0], b[0]);
  o[1] = fminf(fminf(a[1], b[1]), fmaxf(a[0], b[0]));
  o[2] = fminf(fminf(a[2], b[2]), fminf(fmaxf(a[1], b[0]), fmaxf(a[0], b[1])));
  o[3] = fminf(fminf(a[3], b[3]), fminf(fmaxf(a[2], b[0]), fminf(fmaxf(a[1], b[1]), fmaxf(a[0], b[2]))));
  o[4] = fminf(fminf(a[4], b[4]),
               fminf(fmaxf(a[3], b[0]),
                     fminf(fmaxf(a[2], b[1]), fminf(fmaxf(a[1], b[2]), fmaxf(a[0], b[3])))));
}

// ---------------- fused prep (sqn + bf16 cast) + logit losses ----------------
__global__ __launch_bounds__(256) void prep_loss_kernel(const float* __restrict__ X,
                                                        unsigned short* __restrict__ xb,
                                                        float* __restrict__ sqn,
                                                        const float* __restrict__ logit,
                                                        const int* __restrict__ y,
                                                        float* __restrict__ part_cl,
                                                        float* __restrict__ part_ce,
                                                        unsigned int* __restrict__ counter) {
  if (blockIdx.x == 0 && threadIdx.x == 0) *counter = 0u;
  int lane = threadIdx.x & 63;
  if (blockIdx.x < 2048) {
    // prep
    int row = blockIdx.x * 4 + (threadIdx.x >> 6);
    f4 v = ((const f4*)(X + (size_t)row * Dd))[lane];
    float ss = v[0] * v[0] + v[1] * v[1] + v[2] * v[2] + v[3] * v[3];
    ss = wredsum(ss);
    if (lane == 0) sqn[row] = ss;
    ushort4 o;
    o.x = f2bf(v[0]); o.y = f2bf(v[1]); o.z = f2bf(v[2]); o.w = f2bf(v[3]);
    ((ushort4*)(xb + (size_t)row * Dd))[lane] = o;
  } else {
    // loss
    int bid = blockIdx.x - 2048;
    int row = bid * 4 + (threadIdx.x >> 6);
    const float* xr = logit + (size_t)row * Cc;
    float x1 = xr[lane];
    float x2 = (lane == 0) ? xr[64] : -BIGF;
    float mx = wredmax(fmaxf(x1, x2));
    float e1 = expf(x1 - mx);
    float e2 = (lane == 0) ? expf(x2 - mx) : 0.f;
    float Z = wredsum(e1 + e2);
    float res;
    if (row < Ss) {
      int yy = y[row];
      float pick = (lane == yy ? x1 : 0.f) + ((lane == 0 && yy == 64) ? x2 : 0.f);
      float xy = wredsum(pick);
      res = -(xy - mx - logf(Z));
    } else {
      float p1 = e1 / Z;
      float t1 = -p1 * log2f(fmaxf(p1, 1e-8f));
      if (lane == 0) {
        float p2 = e2 / Z;
        t1 += -p2 * log2f(fmaxf(p2, 1e-8f));
      }
      res = wredsum(t1);
    }
    __shared__ float a4[4];
    if (lane == 0) a4[threadIdx.x >> 6] = res;
    __syncthreads();
    if (threadIdx.x == 0) {
      float s = a4[0] + a4[1] + a4[2] + a4[3];
      if (bid < 1024) part_cl[bid] = s;
      else part_ce[bid - 1024] = s;
    }
  }
}

// ---------------- main: MFMA Gram + streaming top-5 ----------------
__device__ __forceinline__ void stage16(const void* g, void* l) {
  __builtin_amdgcn_global_load_lds((__attribute__((address_space(1))) void*)g,
                                   (__attribute__((address_space(3))) void*)l, 16, 0, 0);
}

__global__ __launch_bounds__(256) void dist_kernel(const unsigned short* __restrict__ xb,
                                                   const float* __restrict__ sqn,
                                                   float* __restrict__ top5ws) {
  __shared__ unsigned short ldsA[2][TJ * BK];
  __shared__ unsigned short ldsB[2][TI * BK];

  const int tid = threadIdx.x;
  const int lane = tid & 63;
  const int wv = tid >> 6;
  const int q = lane >> 4;       // quad
  const int c = lane & 15;
  const int jw = wv & 1;
  const int iw = wv >> 1;

  const int ib = (blockIdx.x / NCHUNK) * TI;
  const int chunk = blockIdx.x % NCHUNK;
  const int jc0 = chunk * CHUNK;

  // fragment-read swizzle slot (XOR so b128 reads are 2-way, i.e. free)
  const int swz = q ^ ((lane >> 1) & 3);
  // staging decomposition: lane covers point p = u*16 + pr, 16B slot s = lane&3
  const int pr = lane >> 2;
  const int qd = (lane & 3) ^ ((lane >> 3) & 3); // data 16B-chunk this slot holds
  const int u0 = wv * 2, u1 = wv * 2 + 1;
  const int gcol = qd * 8; // ushort offset of that chunk within a row's 32-k slice

  float top[4][5];
#pragma unroll
  for (int a = 0; a < 4; ++a)
#pragma unroll
    for (int b = 0; b < 5; ++b) top[a][b] = BIGF;

  const int iwbase = ib + iw * 64;

  for (int jt = 0; jt < NJT; ++jt) {
    const int jb = jc0 + jt * TJ;

    f4 acc[4][4];
    f4 z = {0.f, 0.f, 0.f, 0.f};
#pragma unroll
    for (int a = 0; a < 4; ++a)
#pragma unroll
      for (int b2 = 0; b2 < 4; ++b2) acc[a][b2] = z;

    // stage k-slice 0 into buffer 0
    stage16(xb + (size_t)(jb + u0 * 16 + pr) * Dd + gcol, &ldsA[0][u0 * 512]);
    stage16(xb + (size_t)(jb + u1 * 16 + pr) * Dd + gcol, &ldsA[0][u1 * 512]);
    stage16(xb + (size_t)(ib + u0 * 16 + pr) * Dd + gcol, &ldsB[0][u0 * 512]);
    stage16(xb + (size_t)(ib + u1 * 16 + pr) * Dd + gcol, &ldsB[0][u1 * 512]);
    __syncthreads();

#pragma unroll
    for (int ks = 0; ks < KS; ++ks) {
      const int b = ks & 1;
      if (ks + 1 < KS) {
        const int k0 = (ks + 1) * BK;
        stage16(xb + (size_t)(jb + u0 * 16 + pr) * Dd + k0 + gcol, &ldsA[b ^ 1][u0 * 512]);
        stage16(xb + (size_t)(jb + u1 * 16 + pr) * Dd + k0 + gcol, &ldsA[b ^ 1][u1 * 512]);
        stage16(xb + (size_t)(ib + u0 * 16 + pr) * Dd + k0 + gcol, &ldsB[b ^ 1][u0 * 512]);
        stage16(xb + (size_t)(ib + u1 * 16 + pr) * Dd + k0 + gcol, &ldsB[b ^ 1][u1 * 512]);
      }
      bf8 aF[4], bF[4];
#pragma unroll
      for (int rt = 0; rt < 4; ++rt)
        aF[rt] = *(const bf8*)&ldsA[b][(jw * 64 + rt * 16 + c) * 32 + swz * 8];
#pragma unroll
      for (int ct = 0; ct < 4; ++ct)
        bF[ct] = *(const bf8*)&ldsB[b][(iw * 64 + ct * 16 + c) * 32 + swz * 8];
#pragma unroll
      for (int rt = 0; rt < 4; ++rt)
#pragma unroll
        for (int ct = 0; ct < 4; ++ct)
          acc[rt][ct] = __builtin_amdgcn_mfma_f32_16x16x32_bf16(aF[rt], bF[ct], acc[rt][ct], 0, 0, 0);
      __syncthreads();
    }

    // epilogue: t = sqn_j - 2*G  (== d^2 - sqn_i; constant shift per i keeps order)
    const int jrow = jb + jw * 64;
    f4 sq4[4];
#pragma unroll
    for (int rt = 0; rt < 4; ++rt) sq4[rt] = *(const f4*)&sqn[jrow + rt * 16 + q * 4];
    const bool mayDiag = (jrow == iwbase);
#pragma unroll
    for (int ct = 0; ct < 4; ++ct) {
      float t[16];
#pragma unroll
      for (int rt = 0; rt < 4; ++rt)
#pragma unroll
        for (int r = 0; r < 4; ++r)
          t[rt * 4 + r] = fmaf(acc[rt][ct][r], -2.0f, sq4[rt][r]);
      if (mayDiag && ((c >> 2) == q)) t[ct * 4 + (c & 3)] = BIGF; // mask j==i
      float tm = fminf(fminf(fminf(fminf(t[0], t[1]), fminf(t[2], t[3])),
                             fminf(fminf(t[4], t[5]), fminf(t[6], t[7]))),
                       fminf(fminf(fminf(t[8], t[9]), fminf(t[10], t[11])),
                             fminf(fminf(t[12], t[13]), fminf(t[14], t[15]))));
      if (tm < top[ct][4]) {
#pragma unroll
        for (int kk = 0; kk < 16; ++kk) {
          float x = t[kk];
          if (x < top[ct][4]) {
#pragma unroll
            for (int s = 0; s < 4; ++s) {
              float lo = fminf(top[ct][s], x);
              x = fmaxf(top[ct][s], x);
              top[ct][s] = lo;
            }
            top[ct][4] = x;
          }
        }
      }
    }
  }

  // cross-quad merge of sorted-5 lists (all lanes participate in shfl)
  float fin[4][5];
#pragma unroll
  for (int ct = 0; ct < 4; ++ct) {
    float a0 = top[ct][0], a1 = top[ct][1], a2 = top[ct][2], a3 = top[ct][3], a4 = top[ct][4];
#pragma unroll
    for (int off = 16; off <= 32; off <<= 1) {
      float b0 = __shfl_xor(a0, off, 64);
      float b1 = __shfl_xor(a1, off, 64);
      float b2 = __shfl_xor(a2, off, 64);
      float b3 = __shfl_xor(a3, off, 64);
      float b4 = __shfl_xor(a4, off, 64);
      float c0 = fminf(a0, b0);
      float c1 = fminf(fminf(a1, b1), fmaxf(a0, b0));
      float c2 = fminf(fminf(a2, b2), fminf(fmaxf(a1, b0), fmaxf(a0, b1)));
      float c3 = fminf(fminf(a3, b3), fminf(fmaxf(a2, b0), fminf(fmaxf(a1, b1), fmaxf(a0, b2))));
      float c4 = fminf(fminf(a4, b4),
                       fminf(fmaxf(a3, b0),
                             fminf(fmaxf(a2, b1), fminf(fmaxf(a1, b2), fmaxf(a0, b3)))));
      a0 = c0; a1 = c1; a2 = c2; a3 = c3; a4 = c4;
    }
    fin[ct][0] = a0; fin[ct][1] = a1; fin[ct][2] = a2; fin[ct][3] = a3; fin[ct][4] = a4;
  }

  // cross-jw merge via LDS (reuse ldsA; safe: nothing reads staging LDS after last barrier)
  float* mbuf = (float*)ldsA;
  if (jw == 1 && q == 0) {
#pragma unroll
    for (int ct = 0; ct < 4; ++ct) {
      float* m = mbuf + ((((iw << 2) | ct) << 4) + c) * 5;
      m[0] = fin[ct][0]; m[1] = fin[ct][1]; m[2] = fin[ct][2]; m[3] = fin[ct][3]; m[4] = fin[ct][4];
    }
  }
  __syncthreads();
  if (jw == 0 && q == 0) {
#pragma unroll
    for (int ct = 0; ct < 4; ++ct) {
      const float* m = mbuf + ((((iw << 2) | ct) << 4) + c) * 5;
      float bl[5] = {m[0], m[1], m[2], m[3], m[4]};
      float o[5];
      merge5(fin[ct], bl, o);
      int i = iwbase + ct * 16 + c;
      float* dst = top5ws + ((size_t)i * NCHUNK + chunk) * 5;
      dst[0] = o[0]; dst[1] = o[1]; dst[2] = o[2]; dst[3] = o[3]; dst[4] = o[4];
    }
  }
}

// ---------------- merge lists -> loss_reg partials + (last block) final ----------------
__device__ __forceinline__ void merge8lists(const float* L, float* o) {
  float m01[5], m23[5], m45[5], m67[5], mA[5], mB[5];
  merge5(L + 0, L + 5, m01);
  merge5(L + 10, L + 15, m23);
  merge5(L + 20, L + 25, m45);
  merge5(L + 30, L + 35, m67);
  merge5(m01, m23, mA);
  merge5(m45, m67, mB);
  merge5(mA, mB, o);
}

__global__ __launch_bounds__(256) void reg_final_kernel(const float* __restrict__ top5ws,
                                                        const float* __restrict__ sqn,
                                                        float* __restrict__ part_reg,
                                                        const float* __restrict__ part_cl,
                                                        const float* __restrict__ part_ce,
                                                        float* __restrict__ out,
                                                        unsigned int* __restrict__ counter) {
  int i = blockIdx.x * 256 + threadIdx.x;
  float buf[80];
  const float* L = top5ws + (size_t)i * 80;
#pragma unroll
  for (int k = 0; k < 80; ++k) buf[k] = L[k];
  float mlo[5], mhi[5];
  merge8lists(buf, mlo);       // lists over source-half columns (chunks 0..7 = j<4096)
  merge8lists(buf + 40, mhi);  // lists over target-half columns
  bool srcRow = (i < Ss);
  float A0 = srcRow ? mlo[0] : mhi[0]; // intra min (diag excluded)
  float A3 = srcRow ? mlo[3] : mhi[3]; // intra: 4th non-diag == ref's 5th incl diag-0
  float B0 = srcRow ? mhi[0] : mlo[0]; // inter min
  float B4 = srcRow ? mhi[4] : mlo[4]; // inter 5th
  float sq = sqn[i];
  float dmin_a = sqrtf(fmaxf(A0 + sq, 0.f));
  float kth_a = sqrtf(fmaxf(A3 + sq, 0.f));
  float dmin_b = sqrtf(fmaxf(B0 + sq, 0.f));
  float kth_b = sqrtf(fmaxf(B4 + sq, 0.f));
  float sa = expf(-dmin_a / (2.f * (kth_a + 1e-8f)));
  float sb = expf(-dmin_b / (2.f * (kth_b + 1e-8f)));
  float v = fabsf(sa - sb);
  __shared__ float red[256];
  red[threadIdx.x] = v;
  __syncthreads();
#pragma unroll
  for (int s = 128; s; s >>= 1) {
    if (threadIdx.x < s) red[threadIdx.x] += red[threadIdx.x + s];
    __syncthreads();
  }
  if (threadIdx.x == 0) part_reg[blockIdx.x] = red[0];

  // last-block-done: fold the final combine into this kernel (saves a launch)
  __shared__ unsigned int lastFlag;
  __threadfence();
  if (threadIdx.x == 0) lastFlag = (atomicAdd(counter, 1u) == 31u) ? 1u : 0u;
  __syncthreads();
  if (!lastFlag) return;
  __threadfence();  // acquire: all other blocks' part_reg visible

  __shared__ double dred[256];
  int tid = threadIdx.x;
  double a = 0.0;
  for (int k = tid; k < 1024; k += 256) a += (double)part_cl[k];
  dred[tid] = a; __syncthreads();
  for (int s = 128; s; s >>= 1) { if (tid < s) dred[tid] += dred[tid + s]; __syncthreads(); }
  double cl = dred[0]; __syncthreads();
  a = 0.0;
  for (int k = tid; k < 1024; k += 256) a += (double)part_ce[k];
  dred[tid] = a; __syncthreads();
  for (int s = 128; s; s >>= 1) { if (tid < s) dred[tid] += dred[tid + s]; __syncthreads(); }
  double ce = dred[0]; __syncthreads();
  a = (tid < 16) ? (double)part_reg[tid] : 0.0;
  dred[tid] = a; __syncthreads();
  for (int s = 128; s; s >>= 1) { if (tid < s) dred[tid] += dred[tid + s]; __syncthreads(); }
  double rs = dred[0]; __syncthreads();
  a = (tid >= 16 && tid < 32) ? (double)part_reg[tid] : 0.0;
  dred[tid] = a; __syncthreads();
  for (int s = 128; s; s >>= 1) { if (tid < s) dred[tid] += dred[tid + s]; __syncthreads(); }
  if (tid == 0) {
    out[0] = (float)(cl / 4096.0);
    out[1] = (float)(ce / 4096.0);
    out[2] = (float)(rs / 4096.0 + dred[0] / 4096.0);
  }
}

extern "C" void kernel_launch(void* const* d_in, const int* in_sizes, int n_in,
                              void* d_out, int out_size, void* d_ws, size_t ws_size,
                              hipStream_t stream) {
  (void)in_sizes; (void)n_in; (void)out_size; (void)ws_size;
  const float* X = (const float*)d_in[0];
  const float* logit = (const float*)d_in[1];
  const int* y = (const int*)d_in[2];
  float* out = (float*)d_out;
  char* ws = (char*)d_ws;

  unsigned short* xb = (unsigned short*)ws;                 // 4 MB bf16 features
  float* sqn = (float*)(ws + (4u << 20));                   // 32 KB row norms
  float* top5 = (float*)(ws + (4u << 20) + (64u << 10));    // 2.62 MB top-5 lists (16 lists/row)
  float* part_cl = (float*)(ws + (7u << 20));               // partials
  float* part_ce = part_cl + 1024;
  float* part_reg = part_ce + 1024;
  unsigned int* counter = (unsigned int*)(part_reg + 32);

  hipLaunchKernelGGL(prep_loss_kernel, dim3(4096), dim3(256), 0, stream, X, xb, sqn, logit, y,
                     part_cl, part_ce, counter);
  hipLaunchKernelGGL(dist_kernel, dim3((Nn / TI) * NCHUNK), dim3(256), 0, stream, xb, sqn, top5);
  hipLaunchKernelGGL(reg_final_kernel, dim3(32), dim3(256), 0, stream, top5, sqn, part_reg,
                     part_cl, part_ce, out, counter);
}

// Round 2
// 141.428 us; speedup vs baseline: 1.1064x; 1.1064x over previous
//
#include <hip/hip_runtime.h>
#include <stdint.h>

#define Nn 8192
#define Dd 256
#define Ss 4096
#define Cc 65

#define TI 128
#define TJ 128
#define BK 32
#define CHUNK 1024
#define NCHUNK (Nn / CHUNK)   // 8
#define NJT (CHUNK / TJ)      // 8
#define KS (Dd / BK)          // 8

#define BIGF 3.0e37f

typedef float f4 __attribute__((ext_vector_type(4)));
typedef __bf16 bf8 __attribute__((ext_vector_type(8)));

__device__ __forceinline__ float wredsum(float v) {
#pragma unroll
  for (int o = 32; o; o >>= 1) v += __shfl_xor(v, o, 64);
  return v;
}
__device__ __forceinline__ float wredmax(float v) {
#pragma unroll
  for (int o = 32; o; o >>= 1) v = fmaxf(v, __shfl_xor(v, o, 64));
  return v;
}

__device__ __forceinline__ unsigned short f2bf(float f) {
  unsigned int u = __float_as_uint(f);
  u = (u + 0x7fffu + ((u >> 16) & 1u)) >> 16;
  return (unsigned short)u;
}

__device__ __forceinline__ void merge5(const float* a, const float* b, float* o) {
  o[0] = fminf(a[0], b[0]);
  o[1] = fminf(fminf(a[1], b[1]), fmaxf(a[0], b[0]));
  o[2] = fminf(fminf(a[2], b[2]), fminf(fmaxf(a[1], b[0]), fmaxf(a[0], b[1])));
  o[3] = fminf(fminf(a[3], b[3]), fminf(fmaxf(a[2], b[0]), fminf(fmaxf(a[1], b[1]), fmaxf(a[0], b[2]))));
  o[4] = fminf(fminf(a[4], b[4]),
               fminf(fmaxf(a[3], b[0]),
                     fminf(fmaxf(a[2], b[1]), fminf(fmaxf(a[1], b[2]), fmaxf(a[0], b[3])))));
}

// ---------------- fused prep (sqn + bf16 cast) + logit losses ----------------
__global__ __launch_bounds__(256) void prep_loss_kernel(const float* __restrict__ X,
                                                        unsigned short* __restrict__ xb,
                                                        float* __restrict__ sqn,
                                                        const float* __restrict__ logit,
                                                        const int* __restrict__ y,
                                                        float* __restrict__ part_cl,
                                                        float* __restrict__ part_ce,
                                                        unsigned int* __restrict__ counter) {
  if (blockIdx.x == 0 && threadIdx.x == 0) *counter = 0u;
  int lane = threadIdx.x & 63;
  if (blockIdx.x < 2048) {
    // prep
    int row = blockIdx.x * 4 + (threadIdx.x >> 6);
    f4 v = ((const f4*)(X + (size_t)row * Dd))[lane];
    float ss = v[0] * v[0] + v[1] * v[1] + v[2] * v[2] + v[3] * v[3];
    ss = wredsum(ss);
    if (lane == 0) sqn[row] = ss;
    ushort4 o;
    o.x = f2bf(v[0]); o.y = f2bf(v[1]); o.z = f2bf(v[2]); o.w = f2bf(v[3]);
    ((ushort4*)(xb + (size_t)row * Dd))[lane] = o;
  } else {
    // loss
    int bid = blockIdx.x - 2048;
    int row = bid * 4 + (threadIdx.x >> 6);
    const float* xr = logit + (size_t)row * Cc;
    float x1 = xr[lane];
    float x2 = (lane == 0) ? xr[64] : -BIGF;
    float mx = wredmax(fmaxf(x1, x2));
    float e1 = expf(x1 - mx);
    float e2 = (lane == 0) ? expf(x2 - mx) : 0.f;
    float Z = wredsum(e1 + e2);
    float res;
    if (row < Ss) {
      int yy = y[row];
      float pick = (lane == yy ? x1 : 0.f) + ((lane == 0 && yy == 64) ? x2 : 0.f);
      float xy = wredsum(pick);
      res = -(xy - mx - logf(Z));
    } else {
      float p1 = e1 / Z;
      float t1 = -p1 * log2f(fmaxf(p1, 1e-8f));
      if (lane == 0) {
        float p2 = e2 / Z;
        t1 += -p2 * log2f(fmaxf(p2, 1e-8f));
      }
      res = wredsum(t1);
    }
    __shared__ float a4[4];
    if (lane == 0) a4[threadIdx.x >> 6] = res;
    __syncthreads();
    if (threadIdx.x == 0) {
      float s = a4[0] + a4[1] + a4[2] + a4[3];
      if (bid < 1024) part_cl[bid] = s;
      else part_ce[bid - 1024] = s;
    }
  }
}

// ---------------- main: MFMA Gram + streaming top-5 ----------------
__device__ __forceinline__ void stage16(const void* g, void* l) {
  __builtin_amdgcn_global_load_lds((__attribute__((address_space(1))) void*)g,
                                   (__attribute__((address_space(3))) void*)l, 16, 0, 0);
}

// 8 waves/block (512 thr). Per-wave output: 64 j-rows x 32 i-cols -> acc[4][2] (32 AGPR).
// B (i-tile) is LDS-resident for the whole block (64 KB, staged once); A double-buffered.
// __launch_bounds__(512,4): 4 waves/SIMD = 2 blocks/CU; LDS 80KB also = 2 blocks/CU.
__global__ __launch_bounds__(512, 4) void dist_kernel(const unsigned short* __restrict__ xb,
                                                      const float* __restrict__ sqn,
                                                      float* __restrict__ top5ws) {
  __shared__ unsigned short ldsA[2][TJ * BK];    // 16 KB (j-slice double buffer)
  __shared__ unsigned short ldsBf[KS][TI * BK];  // 64 KB (full i-tile, resident)

  const int tid = threadIdx.x;
  const int lane = tid & 63;
  const int wv = tid >> 6;        // 0..7
  const int q = lane >> 4;        // quad
  const int c = lane & 15;
  const int jw = wv & 1;          // j half (64 cols each)
  const int iq = wv >> 1;         // i quarter (32 rows each)

  const int ib = (blockIdx.x / NCHUNK) * TI;
  const int chunk = blockIdx.x % NCHUNK;
  const int jc0 = chunk * CHUNK;

  // fragment-read swizzle slot (XOR so b128 reads are 2-way, i.e. free)
  const int swz = q ^ ((lane >> 1) & 3);
  // staging decomposition: lane covers point p = wv*16 + pr, 16B slot s = lane&3
  const int pr = lane >> 2;
  const int qd = (lane & 3) ^ ((lane >> 3) & 3); // data 16B-chunk this slot holds
  const int gcol = qd * 8; // ushort offset of that chunk within a row's 32-k slice

  float top[2][5];
#pragma unroll
  for (int a = 0; a < 2; ++a)
#pragma unroll
    for (int b = 0; b < 5; ++b) top[a][b] = BIGF;

  const int iwbase = ib + iq * 32;

  // stage resident B (i-tile), all 8 k-slices, once
#pragma unroll
  for (int ks = 0; ks < KS; ++ks)
    stage16(xb + (size_t)(ib + wv * 16 + pr) * Dd + ks * BK + gcol, &ldsBf[ks][wv * 512]);

  for (int jt = 0; jt < NJT; ++jt) {
    const int jb = jc0 + jt * TJ;

    f4 acc[4][2];
    f4 z = {0.f, 0.f, 0.f, 0.f};
#pragma unroll
    for (int a = 0; a < 4; ++a)
#pragma unroll
      for (int b2 = 0; b2 < 2; ++b2) acc[a][b2] = z;

    // stage j k-slice 0 into buffer 0
    stage16(xb + (size_t)(jb + wv * 16 + pr) * Dd + gcol, &ldsA[0][wv * 512]);
    __syncthreads();

#pragma unroll
    for (int ks = 0; ks < KS; ++ks) {
      const int b = ks & 1;
      if (ks + 1 < KS)
        stage16(xb + (size_t)(jb + wv * 16 + pr) * Dd + (ks + 1) * BK + gcol,
                &ldsA[b ^ 1][wv * 512]);
      bf8 aF[4], bF[2];
#pragma unroll
      for (int rt = 0; rt < 4; ++rt)
        aF[rt] = *(const bf8*)&ldsA[b][(jw * 64 + rt * 16 + c) * 32 + swz * 8];
#pragma unroll
      for (int ct = 0; ct < 2; ++ct)
        bF[ct] = *(const bf8*)&ldsBf[ks][(iq * 32 + ct * 16 + c) * 32 + swz * 8];
#pragma unroll
      for (int rt = 0; rt < 4; ++rt)
#pragma unroll
        for (int ct = 0; ct < 2; ++ct)
          acc[rt][ct] = __builtin_amdgcn_mfma_f32_16x16x32_bf16(aF[rt], bF[ct], acc[rt][ct], 0, 0, 0);
      __syncthreads();
    }

    // epilogue: t = sqn_j - 2*G  (== d^2 - sqn_i; constant shift per i keeps order)
    const int jrow = jb + jw * 64;
    f4 sq4[4];
#pragma unroll
    for (int rt = 0; rt < 4; ++rt) sq4[rt] = *(const f4*)&sqn[jrow + rt * 16 + q * 4];
    // diagonal present iff same tile and this wave's 32-row i-range lies in its 64-col j-range
    const bool mayDiag = (jb == ib) && ((iq >> 1) == jw);
#pragma unroll
    for (int ct = 0; ct < 2; ++ct) {
      float t[16];
#pragma unroll
      for (int rt = 0; rt < 4; ++rt)
#pragma unroll
        for (int r = 0; r < 4; ++r)
          t[rt * 4 + r] = fmaf(acc[rt][ct][r], -2.0f, sq4[rt][r]);
      if (mayDiag && ((c >> 2) == q))
        t[((iq & 1) * 2 + ct) * 4 + (c & 3)] = BIGF; // mask j==i
      float tm = fminf(fminf(fminf(fminf(t[0], t[1]), fminf(t[2], t[3])),
                             fminf(fminf(t[4], t[5]), fminf(t[6], t[7]))),
                       fminf(fminf(fminf(t[8], t[9]), fminf(t[10], t[11])),
                             fminf(fminf(t[12], t[13]), fminf(t[14], t[15]))));
      if (tm < top[ct][4]) {
#pragma unroll
        for (int kk = 0; kk < 16; ++kk) {
          float x = t[kk];
          if (x < top[ct][4]) {
#pragma unroll
            for (int s = 0; s < 4; ++s) {
              float lo = fminf(top[ct][s], x);
              x = fmaxf(top[ct][s], x);
              top[ct][s] = lo;
            }
            top[ct][4] = x;
          }
        }
      }
    }
  }

  // cross-quad merge of sorted-5 lists (all lanes participate in shfl)
  float fin[2][5];
#pragma unroll
  for (int ct = 0; ct < 2; ++ct) {
    float a0 = top[ct][0], a1 = top[ct][1], a2 = top[ct][2], a3 = top[ct][3], a4 = top[ct][4];
#pragma unroll
    for (int off = 16; off <= 32; off <<= 1) {
      float b0 = __shfl_xor(a0, off, 64);
      float b1 = __shfl_xor(a1, off, 64);
      float b2 = __shfl_xor(a2, off, 64);
      float b3 = __shfl_xor(a3, off, 64);
      float b4 = __shfl_xor(a4, off, 64);
      float c0 = fminf(a0, b0);
      float c1 = fminf(fminf(a1, b1), fmaxf(a0, b0));
      float c2 = fminf(fminf(a2, b2), fminf(fmaxf(a1, b0), fmaxf(a0, b1)));
      float c3 = fminf(fminf(a3, b3), fminf(fmaxf(a2, b0), fminf(fmaxf(a1, b1), fmaxf(a0, b2))));
      float c4 = fminf(fminf(a4, b4),
                       fminf(fmaxf(a3, b0),
                             fminf(fmaxf(a2, b1), fminf(fmaxf(a1, b2), fmaxf(a0, b3)))));
      a0 = c0; a1 = c1; a2 = c2; a3 = c3; a4 = c4;
    }
    fin[ct][0] = a0; fin[ct][1] = a1; fin[ct][2] = a2; fin[ct][3] = a3; fin[ct][4] = a4;
  }

  // cross-jw merge via LDS (reuse ldsA; safe: no LDS reads after last barrier)
  float* mbuf = (float*)ldsA;
  if (jw == 1 && q == 0) {
#pragma unroll
    for (int ct = 0; ct < 2; ++ct) {
      float* m = mbuf + ((((iq << 1) | ct) << 4) + c) * 5;
      m[0] = fin[ct][0]; m[1] = fin[ct][1]; m[2] = fin[ct][2]; m[3] = fin[ct][3]; m[4] = fin[ct][4];
    }
  }
  __syncthreads();
  if (jw == 0 && q == 0) {
#pragma unroll
    for (int ct = 0; ct < 2; ++ct) {
      const float* m = mbuf + ((((iq << 1) | ct) << 4) + c) * 5;
      float bl[5] = {m[0], m[1], m[2], m[3], m[4]};
      float o[5];
      merge5(fin[ct], bl, o);
      int i = iwbase + ct * 16 + c;
      float* dst = top5ws + ((size_t)i * NCHUNK + chunk) * 5;
      dst[0] = o[0]; dst[1] = o[1]; dst[2] = o[2]; dst[3] = o[3]; dst[4] = o[4];
    }
  }
}

// ---------------- merge lists -> loss_reg partials + (last block) final ----------------
__device__ __forceinline__ void merge4lists(const float* L, float* o) {
  float m01[5], m23[5];
  merge5(L + 0, L + 5, m01);
  merge5(L + 10, L + 15, m23);
  merge5(m01, m23, o);
}

__global__ __launch_bounds__(256) void reg_final_kernel(const float* __restrict__ top5ws,
                                                        const float* __restrict__ sqn,
                                                        float* __restrict__ part_reg,
                                                        const float* __restrict__ part_cl,
                                                        const float* __restrict__ part_ce,
                                                        float* __restrict__ out,
                                                        unsigned int* __restrict__ counter) {
  int i = blockIdx.x * 256 + threadIdx.x;
  float buf[40];
  const float* L = top5ws + (size_t)i * 40;
#pragma unroll
  for (int k = 0; k < 40; ++k) buf[k] = L[k];
  float mlo[5], mhi[5];
  merge4lists(buf, mlo);       // chunks 0..3 = source-half columns (j < 4096)
  merge4lists(buf + 20, mhi);  // chunks 4..7 = target-half columns
  bool srcRow = (i < Ss);
  float A0 = srcRow ? mlo[0] : mhi[0]; // intra min (diag excluded)
  float A3 = srcRow ? mlo[3] : mhi[3]; // intra: 4th non-diag == ref's 5th incl diag-0
  float B0 = srcRow ? mhi[0] : mlo[0]; // inter min
  float B4 = srcRow ? mhi[4] : mlo[4]; // inter 5th
  float sq = sqn[i];
  float dmin_a = sqrtf(fmaxf(A0 + sq, 0.f));
  float kth_a = sqrtf(fmaxf(A3 + sq, 0.f));
  float dmin_b = sqrtf(fmaxf(B0 + sq, 0.f));
  float kth_b = sqrtf(fmaxf(B4 + sq, 0.f));
  float sa = expf(-dmin_a / (2.f * (kth_a + 1e-8f)));
  float sb = expf(-dmin_b / (2.f * (kth_b + 1e-8f)));
  float v = fabsf(sa - sb);
  __shared__ float red[256];
  red[threadIdx.x] = v;
  __syncthreads();
#pragma unroll
  for (int s = 128; s; s >>= 1) {
    if (threadIdx.x < s) red[threadIdx.x] += red[threadIdx.x + s];
    __syncthreads();
  }
  if (threadIdx.x == 0) part_reg[blockIdx.x] = red[0];

  // last-block-done: fold the final combine into this kernel (saves a launch)
  __shared__ unsigned int lastFlag;
  __threadfence();
  if (threadIdx.x == 0) lastFlag = (atomicAdd(counter, 1u) == 31u) ? 1u : 0u;
  __syncthreads();
  if (!lastFlag) return;
  __threadfence();  // acquire: all other blocks' part_reg visible

  __shared__ double dred[256];
  int tid = threadIdx.x;
  double a = 0.0;
  for (int k = tid; k < 1024; k += 256) a += (double)part_cl[k];
  dred[tid] = a; __syncthreads();
  for (int s = 128; s; s >>= 1) { if (tid < s) dred[tid] += dred[tid + s]; __syncthreads(); }
  double cl = dred[0]; __syncthreads();
  a = 0.0;
  for (int k = tid; k < 1024; k += 256) a += (double)part_ce[k];
  dred[tid] = a; __syncthreads();
  for (int s = 128; s; s >>= 1) { if (tid < s) dred[tid] += dred[tid + s]; __syncthreads(); }
  double ce = dred[0]; __syncthreads();
  a = (tid < 16) ? (double)part_reg[tid] : 0.0;
  dred[tid] = a; __syncthreads();
  for (int s = 128; s; s >>= 1) { if (tid < s) dred[tid] += dred[tid + s]; __syncthreads(); }
  double rs = dred[0]; __syncthreads();
  a = (tid >= 16 && tid < 32) ? (double)part_reg[tid] : 0.0;
  dred[tid] = a; __syncthreads();
  for (int s = 128; s; s >>= 1) { if (tid < s) dred[tid] += dred[tid + s]; __syncthreads(); }
  if (tid == 0) {
    out[0] = (float)(cl / 4096.0);
    out[1] = (float)(ce / 4096.0);
    out[2] = (float)(rs / 4096.0 + dred[0] / 4096.0);
  }
}

extern "C" void kernel_launch(void* const* d_in, const int* in_sizes, int n_in,
                              void* d_out, int out_size, void* d_ws, size_t ws_size,
                              hipStream_t stream) {
  (void)in_sizes; (void)n_in; (void)out_size; (void)ws_size;
  const float* X = (const float*)d_in[0];
  const float* logit = (const float*)d_in[1];
  const int* y = (const int*)d_in[2];
  float* out = (float*)d_out;
  char* ws = (char*)d_ws;

  unsigned short* xb = (unsigned short*)ws;                 // 4 MB bf16 features
  float* sqn = (float*)(ws + (4u << 20));                   // 32 KB row norms
  float* top5 = (float*)(ws + (4u << 20) + (64u << 10));    // 1.31 MB top-5 lists (8 lists/row)
  float* part_cl = (float*)(ws + (7u << 20));               // partials
  float* part_ce = part_cl + 1024;
  float* part_reg = part_ce + 1024;
  unsigned int* counter = (unsigned int*)(part_reg + 32);

  hipLaunchKernelGGL(prep_loss_kernel, dim3(4096), dim3(256), 0, stream, X, xb, sqn, logit, y,
                     part_cl, part_ce, counter);
  hipLaunchKernelGGL(dist_kernel, dim3((Nn / TI) * NCHUNK), dim3(512), 0, stream, xb, sqn, top5);
  hipLaunchKernelGGL(reg_final_kernel, dim3(32), dim3(256), 0, stream, top5, sqn, part_reg,
                     part_cl, part_ce, out, counter);
}